// Round 2
// baseline (170.375 us; speedup 1.0000x reference)
//
#include <hip/hip_runtime.h>

#define FF 20
#define DD 16
#define NI 190         // F*(F-1)/2
#define BB 4096
#define FD 320         // F*D
#define RSTR 36        // s_rows padded stride (words): 4-aligned, conflict-free
#define ESTR 17        // s_embw padded stride

// K1: W12[320][190] = senet_w1[320][320] @ senet_w2[320][190]
__global__ __launch_bounds__(192) void k_w12(const float* __restrict__ w1,
                                             const float* __restrict__ w2,
                                             float* __restrict__ W12) {
    __shared__ float srow[FD];
    int r = blockIdx.x;
    for (int j = threadIdx.x; j < FD; j += 192) srow[j] = w1[r * FD + j];
    __syncthreads();
    int c = threadIdx.x;
    if (c < NI) {
        float acc = 0.f;
        for (int k = 0; k < FD; ++k) acc += srow[k] * w2[k * NI + c];
        W12[r * NI + c] = acc;
    }
}

// K2: w[4096][190] = z[4096][320] @ W12[320][190], 16 b-rows per block
__global__ __launch_bounds__(192) void k_w(const float* __restrict__ z,
                                           const float* __restrict__ W12,
                                           float* __restrict__ wout) {
    __shared__ float sz[16 * FD];
    int b0 = blockIdx.x * 16;
    for (int j = threadIdx.x; j < 16 * FD; j += 192) sz[j] = z[b0 * FD + j];
    __syncthreads();
    int c = threadIdx.x;
    if (c < NI) {
        float acc[16];
#pragma unroll
        for (int bb = 0; bb < 16; ++bb) acc[bb] = 0.f;
        for (int k = 0; k < FD; ++k) {
            float wv = W12[k * NI + c];
#pragma unroll
            for (int bb = 0; bb < 16; ++bb) acc[bb] += sz[bb * FD + k] * wv;
        }
#pragma unroll
        for (int bb = 0; bb < 16; ++bb) wout[(b0 + bb) * NI + c] = acc[bb];
    }
}

// K3: fused gather + transform + pair-weighted field reduction. One block per b.
// Phase A: load indices/w/pair-table. Phase B: one-shot gather of all 380 rows
// (1520 independent float4 loads, max MLP). Phase C: 16 threads per pair
// compute emb.w with W column in registers. Phase D: field reduction.
__global__ __launch_bounds__(256) void k_main(const float* __restrict__ cb,   // [500000][16]
                                              const float* __restrict__ Wt,   // [32][16]
                                              const int* __restrict__ hidx,   // [2][B][NI]
                                              const int* __restrict__ iidx,   // [20][19]
                                              const float* __restrict__ wbuf, // [B][NI]
                                              float* __restrict__ out) {      // [B][20][16]
    __shared__ float s_rows[NI * RSTR];    // 190 pairs x 32 row floats (pad 36)
    __shared__ float s_embw[NI * ESTR];    // emb * w per pair (pad 17)
    __shared__ int s_i0[NI], s_i1[NI];
    __shared__ float s_w[NI];
    __shared__ int s_pii[FF * (FF - 1)];

    int t = threadIdx.x;
    int b = blockIdx.x;

    // Phase A: indices + weights + pair table
    for (int j = t; j < NI; j += 256) {
        s_i0[j] = hidx[b * NI + j];
        s_i1[j] = hidx[BB * NI + b * NI + j];
        s_w[j] = wbuf[b * NI + j];
    }
    for (int j = t; j < FF * (FF - 1); j += 256) s_pii[j] = iidx[j];

    // W column for this thread's d (registers), read while Phase A flushes
    int d = t & 15;
    float Wr[32];
#pragma unroll
    for (int k = 0; k < 32; ++k) Wr[k] = Wt[k * 16 + d];
    __syncthreads();

    // Phase B: one-shot gather. task tt in [0,1520): pair=tt>>3, half=(tt>>2)&1,
    // chunk=tt&3. ~6 independent loads per thread.
    const float4* cb4 = (const float4*)cb;
    for (int tt = t; tt < NI * 8; tt += 256) {
        int pair = tt >> 3;
        int half = (tt >> 2) & 1;
        int chunk = tt & 3;
        int row = half ? s_i1[pair] : s_i0[pair];
        float4 v = cb4[row * 4 + chunk];
        *(float4*)&s_rows[pair * RSTR + half * 16 + chunk * 4] = v;
    }
    __syncthreads();

    // Phase C: thread (pp = t>>4, d = t&15); 12 rounds of 16 pairs
    int pp = t >> 4;
#pragma unroll
    for (int rnd = 0; rnd < 12; ++rnd) {
        int pair = rnd * 16 + pp;
        if (pair < NI) {
            const float4* r4 = (const float4*)&s_rows[pair * RSTR];
            float acc = 0.f;
#pragma unroll
            for (int c = 0; c < 8; ++c) {
                float4 v = r4[c];
                acc += v.x * Wr[c * 4 + 0];
                acc += v.y * Wr[c * 4 + 1];
                acc += v.z * Wr[c * 4 + 2];
                acc += v.w * Wr[c * 4 + 3];
            }
            s_embw[pair * ESTR + d] = acc * s_w[pair];
        }
    }
    __syncthreads();

    // Phase D: out[b,i,d] = sum over the 19 pairs containing field i
    for (int o = t; o < FD; o += 256) {
        int i = o >> 4;
        int dd = o & 15;
        float acc = 0.f;
#pragma unroll
        for (int s = 0; s < FF - 1; ++s) {
            int j = s_pii[i * (FF - 1) + s];
            acc += s_embw[j * ESTR + dd];
        }
        out[b * FD + o] = acc;
    }
}

extern "C" void kernel_launch(void* const* d_in, const int* in_sizes, int n_in,
                              void* d_out, int out_size, void* d_ws, size_t ws_size,
                              hipStream_t stream) {
    const float* origin = (const float*)d_in[0];  // (B, F, D) = z
    const float* cb     = (const float*)d_in[1];  // (500000, 16)
    const float* Wt     = (const float*)d_in[2];  // (32, 16)
    const float* w1     = (const float*)d_in[3];  // (320, 320)
    const float* w2     = (const float*)d_in[4];  // (320, 190)
    const int*   hidx   = (const int*)d_in[5];    // (2, B, 190)
    const int*   iidx   = (const int*)d_in[6];    // (20, 19)
    float* out = (float*)d_out;

    float* W12  = (float*)d_ws;          // 320*190 floats
    float* wbuf = W12 + FD * NI;         // 4096*190 floats

    k_w12<<<FD, 192, 0, stream>>>(w1, w2, W12);
    k_w<<<BB / 16, 192, 0, stream>>>(origin, W12, wbuf);
    k_main<<<BB, 256, 0, stream>>>(cb, Wt, hidx, iidx, wbuf, out);
}

// Round 3
// 152.175 us; speedup vs baseline: 1.1196x; 1.1196x over previous
//
#include <hip/hip_runtime.h>

#define FF 20
#define NI 190         // F*(F-1)/2
#define NIP 192        // padded
#define BB 4096
#define FD 320         // F*D
#define RSTR 36        // s_rows padded stride (words): 16B-aligned, conflict-free

// K1: W12p[320][192] = senet_w1[320][320] @ senet_w2[320][190], zero-padded cols
__global__ __launch_bounds__(192) void k_w12(const float* __restrict__ w1,
                                             const float* __restrict__ w2,
                                             float* __restrict__ W12p) {
    __shared__ float srow[FD];
    int r = blockIdx.x;
    for (int j = threadIdx.x; j < FD; j += 192) srow[j] = w1[r * FD + j];
    __syncthreads();
    int c = threadIdx.x;   // 0..191
    float acc = 0.f;
    if (c < NI) {
        for (int k = 0; k < FD; ++k) acc += srow[k] * w2[k * NI + c];
    }
    W12p[r * NIP + c] = acc;
}

// K2: w[4096][192] = z[4096][320] @ W12p[320][192]. 64x64 tiles, 4x4 per thread.
__global__ __launch_bounds__(256) void k_w(const float* __restrict__ z,
                                           const float* __restrict__ W12p,
                                           float* __restrict__ wout) {
    __shared__ float zT[32][68];   // transposed z tile, stride 68: aligned + conflict-free
    __shared__ float Ws[32][64];
    int b0 = blockIdx.x * 64;
    int c0 = blockIdx.y * 64;
    int t = threadIdx.x;
    int tr = t >> 4, tc = t & 15;
    float acc[4][4];
#pragma unroll
    for (int i = 0; i < 4; ++i)
#pragma unroll
        for (int j = 0; j < 4; ++j) acc[i][j] = 0.f;

    for (int k0 = 0; k0 < FD; k0 += 32) {
#pragma unroll
        for (int s = 0; s < 2; ++s) {       // stage zT: 512 float4 tasks
            int task = t + s * 256;
            int row = task >> 3, ch = task & 7;
            float4 v = *(const float4*)&z[(b0 + row) * FD + k0 + ch * 4];
            zT[ch * 4 + 0][row] = v.x;
            zT[ch * 4 + 1][row] = v.y;
            zT[ch * 4 + 2][row] = v.z;
            zT[ch * 4 + 3][row] = v.w;
        }
#pragma unroll
        for (int s = 0; s < 2; ++s) {       // stage Ws
            int task = t + s * 256;
            int kr = task >> 4, cq = task & 15;
            *(float4*)&Ws[kr][cq * 4] = *(const float4*)&W12p[(k0 + kr) * NIP + c0 + cq * 4];
        }
        __syncthreads();
#pragma unroll
        for (int k = 0; k < 32; ++k) {
            float4 zb = *(const float4*)&zT[k][tr * 4];
            float4 wv = *(const float4*)&Ws[k][tc * 4];
            float zz[4] = {zb.x, zb.y, zb.z, zb.w};
            float ww[4] = {wv.x, wv.y, wv.z, wv.w};
#pragma unroll
            for (int i = 0; i < 4; ++i)
#pragma unroll
                for (int j = 0; j < 4; ++j) acc[i][j] += zz[i] * ww[j];
        }
        __syncthreads();
    }
#pragma unroll
    for (int i = 0; i < 4; ++i) {
        float4 v = make_float4(acc[i][0], acc[i][1], acc[i][2], acc[i][3]);
        *(float4*)&wout[(b0 + tr * 4 + i) * NIP + c0 + tc * 4] = v;
    }
}

// K3: fused gather + transform + pair-weighted field reduction. One block per b.
// LDS ~29.6 KB -> 5 blocks/CU. embw overlaid in-place on s_rows (wave-safe).
__global__ __launch_bounds__(256) void k_main(const float* __restrict__ cb,   // [500000][16]
                                              const float* __restrict__ Wt,   // [32][16]
                                              const int* __restrict__ hidx,   // [2][B][NI]
                                              const int* __restrict__ iidx,   // [20][19]
                                              const float* __restrict__ wbuf, // [B][192]
                                              float* __restrict__ out) {      // [B][20][16]
    __shared__ float s_rows[NI * RSTR];
    __shared__ float s_w[NI];
    __shared__ int s_pii[FF * (FF - 1)];

    int t = threadIdx.x;
    int b = blockIdx.x;

    // Phase A: pair weights + pair table (indices read direct from global in B)
    for (int j = t; j < NI; j += 256) s_w[j] = wbuf[b * NIP + j];
    for (int j = t; j < FF * (FF - 1); j += 256) s_pii[j] = iidx[j];

    int d = t & 15;
    float Wr[32];
#pragma unroll
    for (int k = 0; k < 32; ++k) Wr[k] = Wt[k * 16 + d];

    // Phase B: one-shot gather, 6 independent chains per thread.
    const float4* cb4 = (const float4*)cb;
#pragma unroll
    for (int it = 0; it < 6; ++it) {
        int tt = t + it * 256;
        if (tt < NI * 8) {
            int pair = tt >> 3;
            int half = (tt >> 2) & 1;
            int chunk = tt & 3;
            int row = hidx[(half * BB + b) * NI + pair];
            float4 v = cb4[row * 4 + chunk];
            *(float4*)&s_rows[pair * RSTR + half * 16 + chunk * 4] = v;
        }
    }
    __syncthreads();

    // Phase C: thread (pp = t>>4, d = t&15); writes embw in-place into row slot.
    int pp = t >> 4;
#pragma unroll
    for (int rnd = 0; rnd < 12; ++rnd) {
        int pair = rnd * 16 + pp;
        if (pair < NI) {
            const float4* r4 = (const float4*)&s_rows[pair * RSTR];
            float acc = 0.f;
#pragma unroll
            for (int c = 0; c < 8; ++c) {
                float4 v = r4[c];
                acc += v.x * Wr[c * 4 + 0];
                acc += v.y * Wr[c * 4 + 1];
                acc += v.z * Wr[c * 4 + 2];
                acc += v.w * Wr[c * 4 + 3];
            }
            s_rows[pair * RSTR + d] = acc * s_w[pair];  // in-place: row already consumed
        }
    }
    __syncthreads();

    // Phase D: out[b,i,d] = sum over the 19 pairs containing field i
    for (int o = t; o < FD; o += 256) {
        int i = o >> 4;
        int dd = o & 15;
        float acc = 0.f;
#pragma unroll
        for (int s = 0; s < FF - 1; ++s) {
            int j = s_pii[i * (FF - 1) + s];
            acc += s_rows[j * RSTR + dd];
        }
        out[b * FD + o] = acc;
    }
}

extern "C" void kernel_launch(void* const* d_in, const int* in_sizes, int n_in,
                              void* d_out, int out_size, void* d_ws, size_t ws_size,
                              hipStream_t stream) {
    const float* origin = (const float*)d_in[0];  // (B, F, D) = z
    const float* cb     = (const float*)d_in[1];  // (500000, 16)
    const float* Wt     = (const float*)d_in[2];  // (32, 16)
    const float* w1     = (const float*)d_in[3];  // (320, 320)
    const float* w2     = (const float*)d_in[4];  // (320, 190)
    const int*   hidx   = (const int*)d_in[5];    // (2, B, 190)
    const int*   iidx   = (const int*)d_in[6];    // (20, 19)
    float* out = (float*)d_out;

    float* W12p = (float*)d_ws;           // 320*192 floats
    float* wbuf = W12p + FD * NIP;        // 4096*192 floats

    k_w12<<<FD, 192, 0, stream>>>(w1, w2, W12p);
    dim3 gw(BB / 64, 3);
    k_w<<<gw, 256, 0, stream>>>(origin, W12p, wbuf);
    k_main<<<BB, 256, 0, stream>>>(cb, Wt, hidx, iidx, wbuf, out);
}

// Round 4
// 144.752 us; speedup vs baseline: 1.1770x; 1.0513x over previous
//
#include <hip/hip_runtime.h>

#define FF 20
#define NI 190         // F*(F-1)/2
#define NIP 192        // padded
#define BB 4096
#define FD 320         // F*D

// K1: W12p[320][192] = senet_w1[320][320] @ senet_w2[320][190], zero-padded cols
__global__ __launch_bounds__(192) void k_w12(const float* __restrict__ w1,
                                             const float* __restrict__ w2,
                                             float* __restrict__ W12p) {
    __shared__ float srow[FD];
    int r = blockIdx.x;
    for (int j = threadIdx.x; j < FD; j += 192) srow[j] = w1[r * FD + j];
    __syncthreads();
    int c = threadIdx.x;   // 0..191
    float acc = 0.f;
    if (c < NI) {
        for (int k = 0; k < FD; ++k) acc += srow[k] * w2[k * NI + c];
    }
    W12p[r * NIP + c] = acc;
}

// K2: w[4096][192] = z[4096][320] @ W12p[320][192]. 64x64 tiles, 4x4 per thread.
__global__ __launch_bounds__(256) void k_w(const float* __restrict__ z,
                                           const float* __restrict__ W12p,
                                           float* __restrict__ wout) {
    __shared__ float zT[32][68];
    __shared__ float Ws[32][64];
    int b0 = blockIdx.x * 64;
    int c0 = blockIdx.y * 64;
    int t = threadIdx.x;
    int tr = t >> 4, tc = t & 15;
    float acc[4][4];
#pragma unroll
    for (int i = 0; i < 4; ++i)
#pragma unroll
        for (int j = 0; j < 4; ++j) acc[i][j] = 0.f;

    for (int k0 = 0; k0 < FD; k0 += 32) {
#pragma unroll
        for (int s = 0; s < 2; ++s) {
            int task = t + s * 256;
            int row = task >> 3, ch = task & 7;
            float4 v = *(const float4*)&z[(b0 + row) * FD + k0 + ch * 4];
            zT[ch * 4 + 0][row] = v.x;
            zT[ch * 4 + 1][row] = v.y;
            zT[ch * 4 + 2][row] = v.z;
            zT[ch * 4 + 3][row] = v.w;
        }
#pragma unroll
        for (int s = 0; s < 2; ++s) {
            int task = t + s * 256;
            int kr = task >> 4, cq = task & 15;
            *(float4*)&Ws[kr][cq * 4] = *(const float4*)&W12p[(k0 + kr) * NIP + c0 + cq * 4];
        }
        __syncthreads();
#pragma unroll
        for (int k = 0; k < 32; ++k) {
            float4 zb = *(const float4*)&zT[k][tr * 4];
            float4 wv = *(const float4*)&Ws[k][tc * 4];
            float zz[4] = {zb.x, zb.y, zb.z, zb.w};
            float ww[4] = {wv.x, wv.y, wv.z, wv.w};
#pragma unroll
            for (int i = 0; i < 4; ++i)
#pragma unroll
                for (int j = 0; j < 4; ++j) acc[i][j] += zz[i] * ww[j];
        }
        __syncthreads();
    }
#pragma unroll
    for (int i = 0; i < 4; ++i) {
        float4 v = make_float4(acc[i][0], acc[i][1], acc[i][2], acc[i][3]);
        *(float4*)&wout[(b0 + tr * 4 + i) * NIP + c0 + tc * 4] = v;
    }
}

// K3: weighted-sum-first formulation. One block of 320 threads per b.
// thread (f = t>>4, d = t&15): acc_h[d] = sum_{j in pairs(f)} w[j]*cb[idx_h[j]][d]
// then out[b,f,:] = acc0 @ W[0:16] + acc1 @ W[16:32].
// LDS ~8.5 KB -> occupancy wave-limited (6 blocks/CU = 30 waves).
#define SA(f, h, d) ((f) * 33 + (h) * 16 + (d))
__global__ __launch_bounds__(320) void k_main(const float* __restrict__ cb,   // [500000][16]
                                              const float* __restrict__ Wt,   // [32][16]
                                              const int* __restrict__ hidx,   // [2][B][NI]
                                              const int* __restrict__ iidx,   // [20][19]
                                              const float* __restrict__ wbuf, // [B][192]
                                              float* __restrict__ out) {      // [B][20][16]
    __shared__ int s_i0[NI], s_i1[NI];
    __shared__ float s_w[NI];
    __shared__ int s_plist[FF * 19];
    __shared__ float s_W[32 * 16];
    __shared__ float s_acc[19 * 33 + 2 * 16 + 16];

    int t = threadIdx.x;
    int b = blockIdx.x;

    if (t < NI) {
        s_i0[t] = hidx[b * NI + t];
        s_i1[t] = hidx[(BB + b) * NI + t];
        s_w[t] = wbuf[b * NIP + t];
    }
    for (int j = t; j < FF * 19; j += 320) s_plist[j] = iidx[j];
    for (int j = t; j < 512; j += 320) s_W[j] = Wt[j];
    __syncthreads();

    int f = t >> 4, d = t & 15;
    const int* pl = &s_plist[f * 19];
    float a0 = 0.f, a1 = 0.f;
#pragma unroll
    for (int j = 0; j < 19; ++j) {
        int p = pl[j];
        float wv = s_w[p];
        a0 += wv * cb[s_i0[p] * 16 + d];
        a1 += wv * cb[s_i1[p] * 16 + d];
    }
    s_acc[SA(f, 0, d)] = a0;
    s_acc[SA(f, 1, d)] = a1;
    __syncthreads();

    // transform: out[b,f,d] = sum_k acc0[f][k]*W[k][d] + acc1[f][k]*W[16+k][d]
    float r = 0.f;
#pragma unroll
    for (int k = 0; k < 16; ++k) {
        r += s_acc[SA(f, 0, k)] * s_W[k * 16 + d];
        r += s_acc[SA(f, 1, k)] * s_W[(16 + k) * 16 + d];
    }
    out[b * FD + t] = r;
}

extern "C" void kernel_launch(void* const* d_in, const int* in_sizes, int n_in,
                              void* d_out, int out_size, void* d_ws, size_t ws_size,
                              hipStream_t stream) {
    const float* origin = (const float*)d_in[0];  // (B, F, D) = z
    const float* cb     = (const float*)d_in[1];  // (500000, 16)
    const float* Wt     = (const float*)d_in[2];  // (32, 16)
    const float* w1     = (const float*)d_in[3];  // (320, 320)
    const float* w2     = (const float*)d_in[4];  // (320, 190)
    const int*   hidx   = (const int*)d_in[5];    // (2, B, 190)
    const int*   iidx   = (const int*)d_in[6];    // (20, 19)
    float* out = (float*)d_out;

    float* W12p = (float*)d_ws;           // 320*192 floats
    float* wbuf = W12p + FD * NIP;        // 4096*192 floats

    k_w12<<<FD, 192, 0, stream>>>(w1, w2, W12p);
    dim3 gw(BB / 64, 3);
    k_w<<<gw, 256, 0, stream>>>(origin, W12p, wbuf);
    k_main<<<BB, 320, 0, stream>>>(cb, Wt, hidx, iidx, wbuf, out);
}